// Round 1
// baseline (699.258 us; speedup 1.0000x reference)
//
#include <hip/hip_runtime.h>
#include <hip/hip_bf16.h>
#include <cstdint>

// Problem constants
#define LTOK 4096      // H*W*Dd
#define NTOK 8192      // B * L
#define NCH  256       // chunks per sequence (scan)
#define CLEN 16        // chunk length (NCH*CLEN = LTOK)

typedef __attribute__((ext_vector_type(4))) float f32x4;
typedef __attribute__((ext_vector_type(8))) short s16x8;

__device__ __forceinline__ short f2bf(float f) {
  union { float f; unsigned u; } x; x.f = f;
  unsigned r = x.u + 0x7FFFu + ((x.u >> 16) & 1u);
  return (short)(r >> 16);
}

// ---------------------------------------------------------------------------
// K1: transpose (B,DIM,L)->(B,L,DIM), LayerNorm both inputs, keep raw seqT
// grid: B * (L/32) = 256 blocks, 256 threads
// ---------------------------------------------------------------------------
__global__ __launch_bounds__(256) void ln_transpose_kernel(
    const float* __restrict__ in0, const float* __restrict__ in1,
    const float* __restrict__ w0, const float* __restrict__ b0,
    const float* __restrict__ w1, const float* __restrict__ b1,
    float* __restrict__ xln, float* __restrict__ zln, float* __restrict__ seqT)
{
  __shared__ float tile[32 * 257];
  __shared__ float mu[32], rs[32];
  const int tid = threadIdx.x;
  const int b  = blockIdx.x >> 7;
  const int l0 = (blockIdx.x & 127) << 5;

  for (int pass = 0; pass < 2; ++pass) {
    const float* in = pass ? in1 : in0;
    #pragma unroll 8
    for (int i = 0; i < 32; ++i) {
      int e = (i << 8) + tid;
      int c = e >> 5, lo = e & 31;
      tile[lo * 257 + c] = in[((size_t)(b * 256 + c) << 12) + l0 + lo];
    }
    __syncthreads();
    if (tid < 32) {
      float s = 0.f, ss = 0.f;
      #pragma unroll 8
      for (int c = 0; c < 256; ++c) {
        float v = tile[tid * 257 + c];
        s += v; ss += v * v;
      }
      float m = s * (1.f / 256.f);
      float var = ss * (1.f / 256.f) - m * m;
      mu[tid] = m;
      rs[tid] = rsqrtf(var + 1e-5f);
    }
    __syncthreads();
    const float* w  = pass ? w1 : w0;
    const float* bb = pass ? b1 : b0;
    float* dst = pass ? zln : xln;
    float wv = w[tid], bv = bb[tid];
    #pragma unroll 8
    for (int i = 0; i < 32; ++i) {
      float v = tile[i * 257 + tid];
      size_t oidx = (((size_t)b << 12) + l0 + i) * 256 + tid;
      dst[oidx] = (v - mu[i]) * rs[i] * wv + bv;
      if (pass == 0) seqT[oidx] = v;
    }
    __syncthreads();
  }
}

// ---------------------------------------------------------------------------
// K2: bf16 MFMA GEMM, C[M=8192, N] = A[8192,256] * W[N,256]^T
// EPI 0: plain store (stride N)
// EPI 1: += ADD[m*256 + n]  (skip add), stride N=256
// EPI 2: transposed store C[(b*1200+n)*4096 + l] + bias[n]  (conv3d head)
// tile 64x64, 4 waves each computing a 32x32 quadrant (2x2 of 16x16 MFMA)
// ---------------------------------------------------------------------------
template <int EPI>
__global__ __launch_bounds__(256) void gemm256(
    const float* __restrict__ A, const float* __restrict__ W,
    float* __restrict__ C, const float* __restrict__ ADD,
    const float* __restrict__ bias, int N)
{
  __shared__ float smem[4160];                 // 16.6 KB (Cs needs 64*65)
  short* As = (short*)smem;                    // [64][40] bf16
  short* Bs = ((short*)smem) + 64 * 40;        // [64][40] bf16
  float* Cs = smem;                            // [64][65] f32 (EPI2 only)

  const int tid  = threadIdx.x;
  const int lane = tid & 63, wave = tid >> 6;
  const int m0 = blockIdx.y << 6;
  const int n0 = blockIdx.x << 6;
  const int wm = (wave & 1) << 5, wn = (wave >> 1) << 5;
  const int mf = lane & 15;
  const int kq = (lane >> 4) << 3;   // k offset of fragment
  const int rq = (lane >> 4) << 2;   // row offset of C fragment

  f32x4 acc[2][2] = {};

  for (int kt = 0; kt < 256; kt += 32) {
    #pragma unroll
    for (int i = 0; i < 8; ++i) {
      int e = (i << 8) + tid;
      int r = e >> 5, c = e & 31;
      As[r * 40 + c] = f2bf(A[(size_t)(m0 + r) * 256 + kt + c]);
      int n = n0 + r;
      Bs[r * 40 + c] = f2bf(n < N ? W[(size_t)n * 256 + kt + c] : 0.f);
    }
    __syncthreads();
    s16x8 af[2], bf[2];
    #pragma unroll
    for (int i = 0; i < 2; ++i) af[i] = *(const s16x8*)&As[(wm + (i << 4) + mf) * 40 + kq];
    #pragma unroll
    for (int j = 0; j < 2; ++j) bf[j] = *(const s16x8*)&Bs[(wn + (j << 4) + mf) * 40 + kq];
    #pragma unroll
    for (int i = 0; i < 2; ++i)
      #pragma unroll
      for (int j = 0; j < 2; ++j)
        acc[i][j] = __builtin_amdgcn_mfma_f32_16x16x32_bf16(af[i], bf[j], acc[i][j], 0, 0, 0);
    __syncthreads();
  }

  if (EPI < 2) {
    #pragma unroll
    for (int i = 0; i < 2; ++i)
      #pragma unroll
      for (int j = 0; j < 2; ++j)
        #pragma unroll
        for (int r = 0; r < 4; ++r) {
          int gm = m0 + wm + (i << 4) + rq + r;
          int gn = n0 + wn + (j << 4) + mf;
          if (gn < N) {
            float v = acc[i][j][r];
            if (EPI == 1) v += ADD[(size_t)gm * 256 + gn];
            C[(size_t)gm * N + gn] = v;
          }
        }
  } else {
    #pragma unroll
    for (int i = 0; i < 2; ++i)
      #pragma unroll
      for (int j = 0; j < 2; ++j)
        #pragma unroll
        for (int r = 0; r < 4; ++r) {
          int mr = wm + (i << 4) + rq + r;
          int nc = wn + (j << 4) + mf;
          Cs[mr * 65 + nc] = acc[i][j][r];
        }
    __syncthreads();
    int b = m0 >> 12;
    int lbase = m0 & 4095;
    #pragma unroll
    for (int i = 0; i < 16; ++i) {
      int e = (i << 8) + tid;
      int nn = e >> 6, ll = e & 63;
      int gn = n0 + nn;
      if (gn < N)
        C[((size_t)b * 1200 + gn) * 4096 + lbase + ll] = Cs[ll * 65 + nn] + bias[gn];
    }
  }
}

// ---------------------------------------------------------------------------
// K3: causal depthwise conv1d (K=4) + SiLU; output in scan-time order.
// REV=1 : operate on time-reversed x. grid: NTOK blocks, 256 threads (d)
// ---------------------------------------------------------------------------
template <int REV>
__global__ __launch_bounds__(256) void conv_silu_k(
    const float* __restrict__ x, const float* __restrict__ cw,
    const float* __restrict__ cb, float* __restrict__ xc)
{
  const int d = threadIdx.x;
  const int b = blockIdx.x >> 12, t = blockIdx.x & 4095;
  float acc = cb[d];
  #pragma unroll
  for (int k = 0; k < 4; ++k) {
    int ts = t - 3 + k;
    if (ts >= 0) {
      int tn = REV ? (4095 - ts) : ts;
      acc += cw[d * 4 + k] * x[((((size_t)b) << 12) + tn) * 256 + d];
    }
  }
  float sig = 1.f / (1.f + __expf(-acc));
  xc[((((size_t)b) << 12) + t) * 256 + d] = acc * sig;
}

// ---------------------------------------------------------------------------
// K4: dt = softplus(dbl[:, :16] @ dtw^T + bias). grid NTOK, 256 threads (d)
// ---------------------------------------------------------------------------
__global__ __launch_bounds__(256) void dtproj_k(
    const float* __restrict__ dbl, const float* __restrict__ dtw,
    const float* __restrict__ dtb, float* __restrict__ dt)
{
  const int d = threadIdx.x;
  const size_t tok = blockIdx.x;
  __shared__ float row[16];
  if (d < 16) row[d] = dbl[tok * 32 + d];
  __syncthreads();
  float a = dtb[d];
  #pragma unroll
  for (int r = 0; r < 16; ++r) a += row[r] * dtw[d * 16 + r];
  float sp = (a > 20.f) ? a : log1pf(__expf(a));
  dt[tok * 256 + d] = sp;
}

// ---------------------------------------------------------------------------
// Scan (chunked, 3 phases). Per (b,d,n): h_t = exp(dt*A)*h + dt*x*B[t,n].
// Phase1: per-chunk (P = prod dA, Q = in-chunk result from h=0)
// grid: B*NCH blocks (512), 256 threads (d)
// ---------------------------------------------------------------------------
__global__ __launch_bounds__(256) void scan_p1(
    const float* __restrict__ dt, const float* __restrict__ xc,
    const float* __restrict__ dbl, const float* __restrict__ A_log,
    float* __restrict__ P, float* __restrict__ Q)
{
  const int d = threadIdx.x;
  const int b = blockIdx.x >> 8, ch = blockIdx.x & 255;
  float Av[8];
  #pragma unroll
  for (int n = 0; n < 8; ++n) Av[n] = -expf(A_log[(d << 3) + n]);
  float p[8], q[8];
  #pragma unroll
  for (int n = 0; n < 8; ++n) { p[n] = 1.f; q[n] = 0.f; }
  const size_t base = (((size_t)b) << 12) + (ch << 4);
  for (int s = 0; s < CLEN; ++s) {
    size_t tok = base + s;
    float dtv = dt[tok * 256 + d];
    float xv  = xc[tok * 256 + d];
    float du = dtv * xv;
    #pragma unroll
    for (int n = 0; n < 8; ++n) {
      float dA = __expf(dtv * Av[n]);
      p[n] *= dA;
      q[n] = q[n] * dA + du * dbl[tok * 32 + 16 + n];
    }
  }
  size_t ob = ((size_t)(b * NCH + ch) * 8) * 256 + d;
  #pragma unroll
  for (int n = 0; n < 8; ++n) { P[ob + n * 256] = p[n]; Q[ob + n * 256] = q[n]; }
}

// Phase2: inter-chunk scan. grid: B*8 blocks (16), 256 threads (d)
__global__ __launch_bounds__(256) void scan_p2(
    const float* __restrict__ P, const float* __restrict__ Q, float* __restrict__ Hs)
{
  const int d = threadIdx.x;
  const int b = blockIdx.x >> 3, n = blockIdx.x & 7;
  float h = 0.f;
  #pragma unroll 8
  for (int ch = 0; ch < NCH; ++ch) {
    size_t idx = ((size_t)(b * NCH + ch) * 8 + n) * 256 + d;
    Hs[idx] = h;
    h = fmaf(P[idx], h, Q[idx]);
  }
}

// Phase3: replay with true h_start, emit y = (ys + xc*D) * silu(z).
// REV un-reverses the backward direction at write (and reads z at natural t).
// grid: B*NCH blocks (512), 256 threads (d)
template <int REV>
__global__ __launch_bounds__(256) void scan_p3(
    const float* __restrict__ dt, const float* __restrict__ xc,
    const float* __restrict__ dbl, const float* __restrict__ Hs,
    const float* __restrict__ z, const float* __restrict__ A_log,
    const float* __restrict__ Dp, float* __restrict__ y)
{
  const int d = threadIdx.x;
  const int b = blockIdx.x >> 8, ch = blockIdx.x & 255;
  float Av[8], h[8];
  #pragma unroll
  for (int n = 0; n < 8; ++n) Av[n] = -expf(A_log[(d << 3) + n]);
  size_t hb = ((size_t)(b * NCH + ch) * 8) * 256 + d;
  #pragma unroll
  for (int n = 0; n < 8; ++n) h[n] = Hs[hb + n * 256];
  const float Dv = Dp[d];
  const size_t base = (((size_t)b) << 12) + (ch << 4);
  for (int s = 0; s < CLEN; ++s) {
    size_t tok = base + s;
    float dtv = dt[tok * 256 + d];
    float xv  = xc[tok * 256 + d];
    float du = dtv * xv;
    float yv = 0.f;
    #pragma unroll
    for (int n = 0; n < 8; ++n) {
      float dA = __expf(dtv * Av[n]);
      h[n] = h[n] * dA + du * dbl[tok * 32 + 16 + n];
      yv += h[n] * dbl[tok * 32 + 24 + n];
    }
    yv += xv * Dv;
    int t = (int)(tok & 4095);
    int tn = REV ? (4095 - t) : t;
    size_t zi = ((((size_t)b) << 12) + tn) * 256 + d;
    float zv = z[zi];
    y[zi] = yv * zv / (1.f + __expf(-zv));
  }
}

// ---------------------------------------------------------------------------
// K8: RMSNorm (MODE 0: 0.5*(ya+yb), MODE 1: ya). grid NTOK, 256 threads
// ---------------------------------------------------------------------------
template <int MODE>
__global__ __launch_bounds__(256) void rms_k(
    const float* __restrict__ ya, const float* __restrict__ yb,
    const float* __restrict__ w, float* __restrict__ yn)
{
  const int d = threadIdx.x;
  const size_t i = (size_t)blockIdx.x * 256 + d;
  float v = (MODE == 0) ? 0.5f * (ya[i] + yb[i]) : ya[i];
  float ss = v * v;
  #pragma unroll
  for (int o = 32; o > 0; o >>= 1) ss += __shfl_xor(ss, o, 64);
  __shared__ float red[4];
  int lane = d & 63, wv = d >> 6;
  if (lane == 0) red[wv] = ss;
  __syncthreads();
  float tot = red[0] + red[1] + red[2] + red[3];
  float sc = rsqrtf(tot * (1.f / 256.f) + 1e-5f);
  yn[i] = v * sc * w[d];
}

// ---------------------------------------------------------------------------
extern "C" void kernel_launch(void* const* d_in, const int* in_sizes, int n_in,
                              void* d_out, int out_size, void* d_ws, size_t ws_size,
                              hipStream_t stream) {
  const float* in0        = (const float*)d_in[0];
  const float* in1        = (const float*)d_in[1];
  const float* n0w        = (const float*)d_in[2];
  const float* n0b        = (const float*)d_in[3];
  const float* n1w        = (const float*)d_in[4];
  const float* n1b        = (const float*)d_in[5];
  const float* in_proj_w  = (const float*)d_in[6];
  const float* in_projz_w = (const float*)d_in[7];
  const float* conv1d_w   = (const float*)d_in[8];
  const float* conv1d_b   = (const float*)d_in[9];
  const float* conv1db_w  = (const float*)d_in[10];
  const float* conv1db_b  = (const float*)d_in[11];
  const float* xproj_w    = (const float*)d_in[12];
  const float* xprojb_w   = (const float*)d_in[13];
  const float* dtproj_w   = (const float*)d_in[14];
  const float* dtproj_b   = (const float*)d_in[15];
  const float* dtprojb_w  = (const float*)d_in[16];
  const float* dtprojb_b  = (const float*)d_in[17];
  const float* A_log      = (const float*)d_in[18];
  const float* Ab_log     = (const float*)d_in[19];
  const float* D_p        = (const float*)d_in[20];
  const float* D_b        = (const float*)d_in[21];
  const float* rms_w      = (const float*)d_in[22];
  const float* out_proj_w = (const float*)d_in[23];
  const float* conv3d_w   = (const float*)d_in[24];
  const float* conv3d_b   = (const float*)d_in[25];
  (void)in_sizes; (void)n_in; (void)out_size; (void)ws_size;

  float* ws = (float*)d_ws;
  const size_t S = (size_t)NTOK * 256;       // 2,097,152 floats
  float* xln  = ws;            // later: xc (conv output, scan-time order)
  float* zln  = ws + S;        // later: dt buffer
  float* seqT = ws + 2 * S;    // raw transposed input0 (skip)
  float* x    = ws + 3 * S;    // later: yn
  float* z    = ws + 4 * S;    // later: o
  float* yf   = ws + 5 * S;
  float* yb   = ws + 6 * S;
  float* dbl  = ws + 7 * S;                        // NTOK*32
  float* P    = dbl + (size_t)NTOK * 32;           // 2*NCH*8*256 = 1,048,576
  float* Q    = P + (size_t)2 * NCH * 8 * 256;
  float* Hs   = Q + (size_t)2 * NCH * 8 * 256;
  float* xc   = xln;
  float* dtb  = zln;
  float* yn   = x;
  float* obuf = z;
  float* out  = (float*)d_out;

  dim3 blk(256);

  // Stage 1: transpose + LN
  ln_transpose_kernel<<<dim3(256), blk, 0, stream>>>(in0, in1, n0w, n0b, n1w, n1b, xln, zln, seqT);

  // Stage 2: input projections
  gemm256<0><<<dim3(4, 128), blk, 0, stream>>>(xln, in_proj_w, x, nullptr, nullptr, 256);
  gemm256<0><<<dim3(4, 128), blk, 0, stream>>>(zln, in_projz_w, z, nullptr, nullptr, 256);

  // Stage 3: forward direction
  conv_silu_k<0><<<dim3(NTOK), blk, 0, stream>>>(x, conv1d_w, conv1d_b, xc);
  gemm256<0><<<dim3(1, 128), blk, 0, stream>>>(xc, xproj_w, dbl, nullptr, nullptr, 32);
  dtproj_k<<<dim3(NTOK), blk, 0, stream>>>(dbl, dtproj_w, dtproj_b, dtb);
  scan_p1<<<dim3(2 * NCH), blk, 0, stream>>>(dtb, xc, dbl, A_log, P, Q);
  scan_p2<<<dim3(16), blk, 0, stream>>>(P, Q, Hs);
  scan_p3<0><<<dim3(2 * NCH), blk, 0, stream>>>(dtb, xc, dbl, Hs, z, A_log, D_p, yf);

  // Stage 4: backward direction
  conv_silu_k<1><<<dim3(NTOK), blk, 0, stream>>>(x, conv1db_w, conv1db_b, xc);
  gemm256<0><<<dim3(1, 128), blk, 0, stream>>>(xc, xprojb_w, dbl, nullptr, nullptr, 32);
  dtproj_k<<<dim3(NTOK), blk, 0, stream>>>(dbl, dtprojb_w, dtprojb_b, dtb);
  scan_p1<<<dim3(2 * NCH), blk, 0, stream>>>(dtb, xc, dbl, Ab_log, P, Q);
  scan_p2<<<dim3(16), blk, 0, stream>>>(P, Q, Hs);
  scan_p3<1><<<dim3(2 * NCH), blk, 0, stream>>>(dtb, xc, dbl, Hs, z, Ab_log, D_b, yb);

  // Stage 5: three heads (merged, forward, backward)
  const size_t HSZ = (size_t)2 * 1200 * 4096;
  // head 0
  rms_k<0><<<dim3(NTOK), blk, 0, stream>>>(yf, yb, rms_w, yn);
  gemm256<1><<<dim3(4, 128), blk, 0, stream>>>(yn, out_proj_w, obuf, seqT, nullptr, 256);
  gemm256<2><<<dim3(19, 128), blk, 0, stream>>>(obuf, conv3d_w, out, nullptr, conv3d_b, 1200);
  // head 1
  rms_k<1><<<dim3(NTOK), blk, 0, stream>>>(yf, yf, rms_w, yn);
  gemm256<1><<<dim3(4, 128), blk, 0, stream>>>(yn, out_proj_w, obuf, seqT, nullptr, 256);
  gemm256<2><<<dim3(19, 128), blk, 0, stream>>>(obuf, conv3d_w, out + HSZ, nullptr, conv3d_b, 1200);
  // head 2
  rms_k<1><<<dim3(NTOK), blk, 0, stream>>>(yb, yb, rms_w, yn);
  gemm256<1><<<dim3(4, 128), blk, 0, stream>>>(yn, out_proj_w, obuf, seqT, nullptr, 256);
  gemm256<2><<<dim3(19, 128), blk, 0, stream>>>(obuf, conv3d_w, out + 2 * HSZ, nullptr, conv3d_b, 1200);
}

// Round 2
// 402.962 us; speedup vs baseline: 1.7353x; 1.7353x over previous
//
#include <hip/hip_runtime.h>
#include <cstdint>

#define LTOK 4096
#define NTOK 8192
#define NCH  256
#define CLEN 16

typedef __attribute__((ext_vector_type(4))) float f32x4;
typedef __attribute__((ext_vector_type(8))) short s16x8;

__device__ __forceinline__ short f2bf(float f) {
  union { float f; unsigned u; } x; x.f = f;
  unsigned r = x.u + 0x7FFFu + ((x.u >> 16) & 1u);
  return (short)(r >> 16);
}
__device__ __forceinline__ float bf2f(short s) {
  union { float f; unsigned u; } x;
  x.u = ((unsigned)(unsigned short)s) << 16;
  return x.f;
}
__device__ __forceinline__ void gl_lds16(const void* g, void* l) {
  __builtin_amdgcn_global_load_lds((const unsigned int*)g, (unsigned int*)l, 16, 0, 0);
}

// ---------------------------------------------------------------------------
// K0: weight conversion to bf16 (conv3d_w padded 1200->1280 rows with zeros)
// ---------------------------------------------------------------------------
__global__ __launch_bounds__(256) void wconv_k(
    const float* __restrict__ wx, const float* __restrict__ wz,
    const float* __restrict__ wo, const float* __restrict__ wc,
    short* __restrict__ Wx, short* __restrict__ Wz,
    short* __restrict__ Wo, short* __restrict__ Wc)
{
  int idx = blockIdx.x * 256 + threadIdx.x;   // grid 2048 -> 524288
  if (idx < 65536)       Wx[idx] = f2bf(wx[idx]);
  else if (idx < 131072) Wz[idx - 65536] = f2bf(wz[idx - 65536]);
  else if (idx < 196608) Wo[idx - 131072] = f2bf(wo[idx - 131072]);
  else {
    int k = idx - 196608;            // 0..327679  (1280x256)
    int row = k >> 8;
    Wc[k] = (row < 1200) ? f2bf(wc[k]) : (short)0;
  }
}

// ---------------------------------------------------------------------------
// K1: transpose (B,DIM,L)->(B,L,DIM), LayerNorm both inputs (bf16 out), seqT f32
// grid: 256 blocks, 256 threads
// ---------------------------------------------------------------------------
__global__ __launch_bounds__(256) void ln_transpose_kernel(
    const float* __restrict__ in0, const float* __restrict__ in1,
    const float* __restrict__ w0, const float* __restrict__ b0,
    const float* __restrict__ w1, const float* __restrict__ b1,
    short* __restrict__ xlnz, float* __restrict__ seqT)
{
  __shared__ float tile[32 * 257];
  __shared__ float mu[32], rs[32];
  const int tid = threadIdx.x;
  const int b  = blockIdx.x >> 7;
  const int l0 = (blockIdx.x & 127) << 5;

  for (int pass = 0; pass < 2; ++pass) {
    const float* in = pass ? in1 : in0;
    #pragma unroll 8
    for (int i = 0; i < 32; ++i) {
      int e = (i << 8) + tid;
      int c = e >> 5, lo = e & 31;
      tile[lo * 257 + c] = in[((size_t)(b * 256 + c) << 12) + l0 + lo];
    }
    __syncthreads();
    if (tid < 32) {
      float s = 0.f, ss = 0.f;
      #pragma unroll 8
      for (int c = 0; c < 256; ++c) {
        float v = tile[tid * 257 + c];
        s += v; ss += v * v;
      }
      float m = s * (1.f / 256.f);
      float var = ss * (1.f / 256.f) - m * m;
      mu[tid] = m;
      rs[tid] = rsqrtf(var + 1e-5f);
    }
    __syncthreads();
    const float* w  = pass ? w1 : w0;
    const float* bb = pass ? b1 : b0;
    float wv = w[tid], bv = bb[tid];
    #pragma unroll 8
    for (int i = 0; i < 32; ++i) {
      float v = tile[i * 257 + tid];
      int row = (pass ? 8192 : 0) + (b << 12) + l0 + i;
      xlnz[(size_t)row * 256 + tid] = f2bf((v - mu[i]) * rs[i] * wv + bv);
      if (pass == 0) seqT[(((size_t)b << 12) + l0 + i) * 256 + tid] = v;
    }
    __syncthreads();
  }
}

// ---------------------------------------------------------------------------
// K2: fast 128x128 bf16 MFMA GEMM, C[M,N=...] = A[M,256] * W[N,256]^T
// A, W pre-converted bf16. global_load_lds width-16 staging (m97 structure).
// EPI 0: f32 store, N=256; W switches W0->W1 at m>=Msplit (in_proj x|z)
// EPI 1: bf16 store + f32 ADD[(m&8191)*256+n]  (out_proj + skip, batched heads)
// EPI 2: conv3d: transposed f32x4 store out[head][(b*1200+n)*4096+l] + bias[n]
// ---------------------------------------------------------------------------
template <int EPI>
__global__ __launch_bounds__(256) void gemm_fast(
    const short* __restrict__ A, const short* __restrict__ W0,
    const short* __restrict__ W1, float* __restrict__ Cf,
    short* __restrict__ Cb, const float* __restrict__ ADD,
    const float* __restrict__ bias, int Msplit)
{
  __shared__ short As[4096];   // [128][32] bf16, unpadded (global_load_lds)
  __shared__ short Bs[4096];
  const int tid  = threadIdx.x;
  const int lane = tid & 63, wave = tid >> 6;
  const int m0 = blockIdx.y << 7;
  const int n0 = blockIdx.x << 7;
  const short* W = (EPI == 0 && m0 >= Msplit) ? W1 : W0;

  const int sr = tid >> 2;            // staging row 0..63 (per 64-row group)
  const int sc = (tid & 3) << 3;      // staging col 0,8,16,24
  const int mf = lane & 15, kq = lane >> 4;
  const int wm = (wave & 1) << 6, wn = (wave >> 1) << 6;

  const short* Ar0 = A + (size_t)(m0 + sr) * 256 + sc;
  const short* Ar1 = A + (size_t)(m0 + 64 + sr) * 256 + sc;
  const short* Br0 = W + (size_t)(n0 + sr) * 256 + sc;
  const short* Br1 = W + (size_t)(n0 + 64 + sr) * 256 + sc;
  short* AsW = &As[wave << 9];        // wave-uniform LDS base (HW adds lane*16B)
  short* BsW = &Bs[wave << 9];

  f32x4 acc[4][4] = {};

  for (int kt = 0; kt < 256; kt += 32) {
    gl_lds16(Ar0 + kt, AsW);
    gl_lds16(Ar1 + kt, AsW + 2048);
    gl_lds16(Br0 + kt, BsW);
    gl_lds16(Br1 + kt, BsW + 2048);
    __syncthreads();
    s16x8 af[4], bfr[4];
    #pragma unroll
    for (int i = 0; i < 4; ++i)
      af[i] = *(const s16x8*)&As[((wm + (i << 4) + mf) << 5) + (kq << 3)];
    #pragma unroll
    for (int j = 0; j < 4; ++j)
      bfr[j] = *(const s16x8*)&Bs[((wn + (j << 4) + mf) << 5) + (kq << 3)];
    #pragma unroll
    for (int i = 0; i < 4; ++i)
      #pragma unroll
      for (int j = 0; j < 4; ++j)
        acc[i][j] = __builtin_amdgcn_mfma_f32_16x16x32_bf16(af[i], bfr[j], acc[i][j], 0, 0, 0);
    __syncthreads();
  }

  if (EPI == 0) {
    #pragma unroll
    for (int i = 0; i < 4; ++i) {
      int gm = m0 + wm + (i << 4) + (kq << 2);
      #pragma unroll
      for (int j = 0; j < 4; ++j) {
        int gn = n0 + wn + (j << 4) + mf;
        #pragma unroll
        for (int r = 0; r < 4; ++r)
          Cf[(size_t)(gm + r) * 256 + gn] = acc[i][j][r];
      }
    }
  } else if (EPI == 1) {
    #pragma unroll
    for (int i = 0; i < 4; ++i) {
      int gm = m0 + wm + (i << 4) + (kq << 2);
      #pragma unroll
      for (int j = 0; j < 4; ++j) {
        int gn = n0 + wn + (j << 4) + mf;
        #pragma unroll
        for (int r = 0; r < 4; ++r) {
          int tok = (gm + r) & 8191;
          float v = acc[i][j][r] + ADD[(size_t)tok * 256 + gn];
          Cb[(size_t)(gm + r) * 256 + gn] = f2bf(v);
        }
      }
    }
  } else {
    const int head = m0 >> 13, bb = (m0 >> 12) & 1, lb = m0 & 4095;
    float* obase = Cf + (size_t)head * (2u * 1200u * 4096u) + (size_t)bb * (1200u * 4096u);
    #pragma unroll
    for (int i = 0; i < 4; ++i) {
      int l = lb + wm + (i << 4) + (kq << 2);
      #pragma unroll
      for (int j = 0; j < 4; ++j) {
        int gn = n0 + wn + (j << 4) + mf;
        if (gn < 1200) {
          float bv = bias[gn];
          f32x4 v = acc[i][j];
          v[0] += bv; v[1] += bv; v[2] += bv; v[3] += bv;
          *(f32x4*)&obase[(size_t)gn * 4096 + l] = v;
        }
      }
    }
  }
}

// ---------------------------------------------------------------------------
// K2b: legacy 64x64 GEMM for xproj (N=32, f32 inputs), C f32 [M][N]
// ---------------------------------------------------------------------------
__global__ __launch_bounds__(256) void gemm_small(
    const float* __restrict__ A, const float* __restrict__ W,
    float* __restrict__ C, int N)
{
  __shared__ float smem[2560];
  short* As = (short*)smem;
  short* Bs = ((short*)smem) + 64 * 40;
  const int tid  = threadIdx.x;
  const int lane = tid & 63, wave = tid >> 6;
  const int m0 = blockIdx.y << 6;
  const int n0 = blockIdx.x << 6;
  const int wm = (wave & 1) << 5, wn = (wave >> 1) << 5;
  const int mf = lane & 15;
  const int kq = (lane >> 4) << 3;
  const int rq = (lane >> 4) << 2;
  f32x4 acc[2][2] = {};
  for (int kt = 0; kt < 256; kt += 32) {
    #pragma unroll
    for (int i = 0; i < 8; ++i) {
      int e = (i << 8) + tid;
      int r = e >> 5, c = e & 31;
      As[r * 40 + c] = f2bf(A[(size_t)(m0 + r) * 256 + kt + c]);
      int n = n0 + r;
      Bs[r * 40 + c] = f2bf(n < N ? W[(size_t)n * 256 + kt + c] : 0.f);
    }
    __syncthreads();
    s16x8 af[2], bfr[2];
    #pragma unroll
    for (int i = 0; i < 2; ++i) af[i] = *(const s16x8*)&As[(wm + (i << 4) + mf) * 40 + kq];
    #pragma unroll
    for (int j = 0; j < 2; ++j) bfr[j] = *(const s16x8*)&Bs[(wn + (j << 4) + mf) * 40 + kq];
    #pragma unroll
    for (int i = 0; i < 2; ++i)
      #pragma unroll
      for (int j = 0; j < 2; ++j)
        acc[i][j] = __builtin_amdgcn_mfma_f32_16x16x32_bf16(af[i], bfr[j], acc[i][j], 0, 0, 0);
    __syncthreads();
  }
  #pragma unroll
  for (int i = 0; i < 2; ++i)
    #pragma unroll
    for (int j = 0; j < 2; ++j)
      #pragma unroll
      for (int r = 0; r < 4; ++r) {
        int gm = m0 + wm + (i << 4) + rq + r;
        int gn = n0 + wn + (j << 4) + mf;
        if (gn < N) C[(size_t)gm * N + gn] = acc[i][j][r];
      }
}

// ---------------------------------------------------------------------------
// K3: causal depthwise conv1d (K=4) + SiLU, 16 tokens per block.
// grid: B*256 blocks, 256 threads (d)
// ---------------------------------------------------------------------------
template <int REV>
__global__ __launch_bounds__(256) void conv_silu_k(
    const float* __restrict__ x, const float* __restrict__ cw,
    const float* __restrict__ cb, float* __restrict__ xc)
{
  const int d = threadIdx.x;
  const int b = blockIdx.x >> 8;
  const int t0 = (blockIdx.x & 255) << 4;
  const float w0 = cw[(d << 2)], w1 = cw[(d << 2) + 1],
              w2 = cw[(d << 2) + 2], w3 = cw[(d << 2) + 3];
  const float bias = cb[d];
  const size_t xb = ((size_t)b) << 12;
  float h0 = 0.f, h1 = 0.f, h2 = 0.f;
  #pragma unroll
  for (int i = 0; i < 3; ++i) {
    int ts = t0 - 3 + i;
    float v = 0.f;
    if (ts >= 0) { int tn = REV ? 4095 - ts : ts; v = x[(xb + tn) * 256 + d]; }
    h0 = h1; h1 = h2; h2 = v;
  }
  for (int s = 0; s < 16; ++s) {
    int ts = t0 + s;
    int tn = REV ? 4095 - ts : ts;
    float xv = x[(xb + tn) * 256 + d];
    float a = bias + w0 * h0 + w1 * h1 + w2 * h2 + w3 * xv;
    h0 = h1; h1 = h2; h2 = xv;
    xc[(xb + ts) * 256 + d] = a / (1.f + __expf(-a));
  }
}

// ---------------------------------------------------------------------------
// Scan phase 1 (fused dtproj): per-chunk (P,Q). grid B*NCH=512, 256 threads
// ---------------------------------------------------------------------------
__global__ __launch_bounds__(256) void scan_p1(
    const float* __restrict__ xc, const float* __restrict__ dbl,
    const float* __restrict__ dtw, const float* __restrict__ dtb,
    const float* __restrict__ A_log, float* __restrict__ P, float* __restrict__ Q)
{
  __shared__ float dl[512];
  const int d = threadIdx.x;
  const int b = blockIdx.x >> 8, ch = blockIdx.x & 255;
  const int tok0 = (b << 12) + (ch << 4);
  dl[d]       = dbl[(size_t)tok0 * 32 + d];
  dl[256 + d] = dbl[(size_t)tok0 * 32 + 256 + d];
  float wrow[16];
  #pragma unroll
  for (int r = 0; r < 16; ++r) wrow[r] = dtw[(d << 4) + r];
  const float bias = dtb[d];
  float Av[8], p[8], q[8];
  #pragma unroll
  for (int n = 0; n < 8; ++n) { Av[n] = -expf(A_log[(d << 3) + n]); p[n] = 1.f; q[n] = 0.f; }
  __syncthreads();
  for (int s = 0; s < 16; ++s) {
    float a = bias;
    #pragma unroll
    for (int r = 0; r < 16; ++r) a = fmaf(dl[(s << 5) + r], wrow[r], a);
    float dtv = (a > 20.f) ? a : log1pf(__expf(a));
    size_t tok = (size_t)tok0 + s;
    float xv = xc[tok * 256 + d];
    float du = dtv * xv;
    #pragma unroll
    for (int n = 0; n < 8; ++n) {
      float dA = __expf(dtv * Av[n]);
      p[n] *= dA;
      q[n] = fmaf(q[n], dA, du * dl[(s << 5) + 16 + n]);
    }
  }
  size_t ob = ((size_t)((b << 8) + ch) * 8) * 256 + d;
  #pragma unroll
  for (int n = 0; n < 8; ++n) { P[ob + (n << 8)] = p[n]; Q[ob + (n << 8)] = q[n]; }
}

// Phase 2a: compose 16 chunks per superchunk. grid B*8*16=256, 256 threads
__global__ __launch_bounds__(256) void scan_p2a(
    const float* __restrict__ P, const float* __restrict__ Q,
    float* __restrict__ SP, float* __restrict__ SQ)
{
  const int d = threadIdx.x;
  const int bidx = blockIdx.x;
  const int b = bidx >> 7, n = (bidx >> 4) & 7, sup = bidx & 15;
  float sp = 1.f, sq = 0.f;
  #pragma unroll 4
  for (int c = 0; c < 16; ++c) {
    int ch = (sup << 4) + c;
    size_t idx = ((size_t)((b << 8) + ch) * 8 + n) * 256 + d;
    float pp = P[idx], qq = Q[idx];
    sq = fmaf(pp, sq, qq);
    sp *= pp;
  }
  size_t o2 = ((size_t)(((b << 3) + n) << 4) + sup) * 256 + d;
  SP[o2] = sp; SQ[o2] = sq;
}

// Phase 2b: serial scan over 16 superchunks. grid B*8=16, 256 threads
__global__ __launch_bounds__(256) void scan_p2b(
    const float* __restrict__ SP, const float* __restrict__ SQ, float* __restrict__ SH)
{
  const int d = threadIdx.x;
  const int bn = blockIdx.x;
  float h = 0.f;
  #pragma unroll 4
  for (int sup = 0; sup < 16; ++sup) {
    size_t i = ((size_t)(bn << 4) + sup) * 256 + d;
    SH[i] = h;
    h = fmaf(SP[i], h, SQ[i]);
  }
}

// Phase 2c: expand to per-chunk start states Hs. grid 256, 256 threads
__global__ __launch_bounds__(256) void scan_p2c(
    const float* __restrict__ P, const float* __restrict__ Q,
    const float* __restrict__ SH, float* __restrict__ Hs)
{
  const int d = threadIdx.x;
  const int bidx = blockIdx.x;
  const int b = bidx >> 7, n = (bidx >> 4) & 7, sup = bidx & 15;
  float h = SH[((size_t)(((b << 3) + n) << 4) + sup) * 256 + d];
  #pragma unroll 4
  for (int c = 0; c < 16; ++c) {
    int ch = (sup << 4) + c;
    size_t idx = ((size_t)((b << 8) + ch) * 8 + n) * 256 + d;
    Hs[idx] = h;
    h = fmaf(P[idx], h, Q[idx]);
  }
}

// Phase 3 (fused dtproj + gate): emit y bf16. grid B*NCH=512, 256 threads
template <int REV>
__global__ __launch_bounds__(256) void scan_p3(
    const float* __restrict__ xc, const float* __restrict__ dbl,
    const float* __restrict__ dtw, const float* __restrict__ dtb,
    const float* __restrict__ Hs, const float* __restrict__ z,
    const float* __restrict__ A_log, const float* __restrict__ Dp,
    short* __restrict__ y)
{
  __shared__ float dl[512];
  const int d = threadIdx.x;
  const int b = blockIdx.x >> 8, ch = blockIdx.x & 255;
  const int tok0 = (b << 12) + (ch << 4);
  dl[d]       = dbl[(size_t)tok0 * 32 + d];
  dl[256 + d] = dbl[(size_t)tok0 * 32 + 256 + d];
  float wrow[16];
  #pragma unroll
  for (int r = 0; r < 16; ++r) wrow[r] = dtw[(d << 4) + r];
  const float bias = dtb[d];
  float Av[8], h[8];
  #pragma unroll
  for (int n = 0; n < 8; ++n) Av[n] = -expf(A_log[(d << 3) + n]);
  size_t hb = ((size_t)((b << 8) + ch) * 8) * 256 + d;
  #pragma unroll
  for (int n = 0; n < 8; ++n) h[n] = Hs[hb + (n << 8)];
  const float Dv = Dp[d];
  __syncthreads();
  for (int s = 0; s < 16; ++s) {
    float a = bias;
    #pragma unroll
    for (int r = 0; r < 16; ++r) a = fmaf(dl[(s << 5) + r], wrow[r], a);
    float dtv = (a > 20.f) ? a : log1pf(__expf(a));
    size_t tok = (size_t)tok0 + s;
    float xv = xc[tok * 256 + d];
    float du = dtv * xv;
    float yv = 0.f;
    #pragma unroll
    for (int n = 0; n < 8; ++n) {
      float dA = __expf(dtv * Av[n]);
      h[n] = fmaf(h[n], dA, du * dl[(s << 5) + 16 + n]);
      yv = fmaf(h[n], dl[(s << 5) + 24 + n], yv);
    }
    yv = fmaf(xv, Dv, yv);
    int t = (int)(tok & 4095);
    int tn = REV ? (4095 - t) : t;
    size_t zi = (((size_t)b << 12) + tn) * 256 + d;
    float zv = z[zi];
    y[zi] = f2bf(yv * zv / (1.f + __expf(-zv)));
  }
}

// ---------------------------------------------------------------------------
// K8: RMSNorm all 3 heads (mode=blockIdx.y: 0=avg, 1=yf, 2=yb), bf16 in/out
// ---------------------------------------------------------------------------
__global__ __launch_bounds__(256) void rms_all(
    const short* __restrict__ yf, const short* __restrict__ yb,
    const float* __restrict__ w, short* __restrict__ yn)
{
  const int d = threadIdx.x;
  const int mode = blockIdx.y;
  const size_t tok = blockIdx.x;
  size_t i = tok * 256 + d;
  float v;
  if (mode == 0)      v = 0.5f * (bf2f(yf[i]) + bf2f(yb[i]));
  else if (mode == 1) v = bf2f(yf[i]);
  else                v = bf2f(yb[i]);
  float ss = v * v;
  #pragma unroll
  for (int o = 32; o > 0; o >>= 1) ss += __shfl_xor(ss, o, 64);
  __shared__ float red[4];
  if ((d & 63) == 0) red[d >> 6] = ss;
  __syncthreads();
  float tot = red[0] + red[1] + red[2] + red[3];
  float sc = rsqrtf(tot * (1.f / 256.f) + 1e-5f);
  yn[((size_t)mode * 8192 + tok) * 256 + d] = f2bf(v * sc * w[d]);
}

// ---------------------------------------------------------------------------
extern "C" void kernel_launch(void* const* d_in, const int* in_sizes, int n_in,
                              void* d_out, int out_size, void* d_ws, size_t ws_size,
                              hipStream_t stream) {
  const float* in0        = (const float*)d_in[0];
  const float* in1        = (const float*)d_in[1];
  const float* n0w        = (const float*)d_in[2];
  const float* n0b        = (const float*)d_in[3];
  const float* n1w        = (const float*)d_in[4];
  const float* n1b        = (const float*)d_in[5];
  const float* in_proj_w  = (const float*)d_in[6];
  const float* in_projz_w = (const float*)d_in[7];
  const float* conv1d_w   = (const float*)d_in[8];
  const float* conv1d_b   = (const float*)d_in[9];
  const float* conv1db_w  = (const float*)d_in[10];
  const float* conv1db_b  = (const float*)d_in[11];
  const float* xproj_w    = (const float*)d_in[12];
  const float* xprojb_w   = (const float*)d_in[13];
  const float* dtproj_w   = (const float*)d_in[14];
  const float* dtproj_b   = (const float*)d_in[15];
  const float* dtprojb_w  = (const float*)d_in[16];
  const float* dtprojb_b  = (const float*)d_in[17];
  const float* A_log      = (const float*)d_in[18];
  const float* Ab_log     = (const float*)d_in[19];
  const float* D_p        = (const float*)d_in[20];
  const float* D_b        = (const float*)d_in[21];
  const float* rms_w      = (const float*)d_in[22];
  const float* out_proj_w = (const float*)d_in[23];
  const float* conv3d_w   = (const float*)d_in[24];
  const float* conv3d_b   = (const float*)d_in[25];
  (void)in_sizes; (void)n_in; (void)out_size; (void)ws_size;

  float* ws = (float*)d_ws;
  size_t o = 0;
  short* xlnz = (short*)(ws + o); o += 2097152;   // 16384x256 bf16
  float* seqT = ws + o;           o += 2097152;
  float* x    = ws + o;           o += 2097152;   // x then z contiguous
  float* z    = ws + o;           o += 2097152;
  float* xc   = ws + o;           o += 2097152;
  float* dbl  = ws + o;           o += 262144;
  float* P    = ws + o;           o += 1048576;
  float* Q    = ws + o;           o += 1048576;
  float* Hs   = ws + o;           o += 1048576;
  float* SP   = ws + o;           o += 65536;
  float* SQ   = ws + o;           o += 65536;
  float* SH   = ws + o;           o += 65536;
  short* yfb  = (short*)(ws + o); o += 1048576;   // 8192x256 bf16
  short* ybb  = (short*)(ws + o); o += 1048576;
  short* yn   = (short*)(ws + o); o += 3145728;   // 24576x256 bf16
  short* obuf = (short*)(ws + o); o += 3145728;
  short* Wx   = (short*)(ws + o); o += 32768;
  short* Wz   = (short*)(ws + o); o += 32768;
  short* Wo   = (short*)(ws + o); o += 32768;
  short* Wc   = (short*)(ws + o); o += 163840;    // 1280x256 bf16 (padded)
  float* out  = (float*)d_out;

  dim3 blk(256);

  wconv_k<<<dim3(2048), blk, 0, stream>>>(in_proj_w, in_projz_w, out_proj_w, conv3d_w, Wx, Wz, Wo, Wc);
  ln_transpose_kernel<<<dim3(256), blk, 0, stream>>>(in0, in1, n0w, n0b, n1w, n1b, xlnz, seqT);

  // in_proj: x|z batched (M=16384, weight switch at 8192)
  gemm_fast<0><<<dim3(2, 128), blk, 0, stream>>>(xlnz, Wx, Wz, x, nullptr, nullptr, nullptr, 8192);

  // forward direction
  conv_silu_k<0><<<dim3(512), blk, 0, stream>>>(x, conv1d_w, conv1d_b, xc);
  gemm_small<<<dim3(1, 128), blk, 0, stream>>>(xc, xproj_w, dbl, 32);
  scan_p1<<<dim3(512), blk, 0, stream>>>(xc, dbl, dtproj_w, dtproj_b, A_log, P, Q);
  scan_p2a<<<dim3(256), blk, 0, stream>>>(P, Q, SP, SQ);
  scan_p2b<<<dim3(16), blk, 0, stream>>>(SP, SQ, SH);
  scan_p2c<<<dim3(256), blk, 0, stream>>>(P, Q, SH, Hs);
  scan_p3<0><<<dim3(512), blk, 0, stream>>>(xc, dbl, dtproj_w, dtproj_b, Hs, z, A_log, D_p, yfb);

  // backward direction
  conv_silu_k<1><<<dim3(512), blk, 0, stream>>>(x, conv1db_w, conv1db_b, xc);
  gemm_small<<<dim3(1, 128), blk, 0, stream>>>(xc, xprojb_w, dbl, 32);
  scan_p1<<<dim3(512), blk, 0, stream>>>(xc, dbl, dtprojb_w, dtprojb_b, Ab_log, P, Q);
  scan_p2a<<<dim3(256), blk, 0, stream>>>(P, Q, SP, SQ);
  scan_p2b<<<dim3(16), blk, 0, stream>>>(SP, SQ, SH);
  scan_p2c<<<dim3(256), blk, 0, stream>>>(P, Q, SH, Hs);
  scan_p3<1><<<dim3(512), blk, 0, stream>>>(xc, dbl, dtprojb_w, dtprojb_b, Hs, z, Ab_log, D_b, ybb);

  // heads: rms (3 modes) -> out_proj+skip (batched) -> conv3d (batched)
  rms_all<<<dim3(8192, 3), blk, 0, stream>>>(yfb, ybb, rms_w, yn);
  gemm_fast<1><<<dim3(2, 192), blk, 0, stream>>>(yn, Wo, nullptr, nullptr, obuf, seqT, nullptr, 0);
  gemm_fast<2><<<dim3(10, 192), blk, 0, stream>>>(obuf, Wc, nullptr, out, nullptr, nullptr, conv3d_b, 0);
}

// Round 3
// 338.977 us; speedup vs baseline: 2.0628x; 1.1888x over previous
//
#include <hip/hip_runtime.h>
#include <cstdint>

#define NTOK 8192

typedef __attribute__((ext_vector_type(4))) float f32x4;
typedef __attribute__((ext_vector_type(8))) short s16x8;

__device__ __forceinline__ short f2bf(float f) {
  union { float f; unsigned u; } x; x.f = f;
  unsigned r = x.u + 0x7FFFu + ((x.u >> 16) & 1u);
  return (short)(r >> 16);
}
__device__ __forceinline__ float bf2f(short s) {
  union { float f; unsigned u; } x;
  x.u = ((unsigned)(unsigned short)s) << 16;
  return x.f;
}
__device__ __forceinline__ void gl_lds16(const void* g, void* l) {
  __builtin_amdgcn_global_load_lds((const unsigned int*)g, (unsigned int*)l, 16, 0, 0);
}

// ---------------------------------------------------------------------------
// K1: transpose (B,DIM,L)->(B,L,DIM) + LayerNorm both inputs (bf16 out),
// seqT f32; ALSO converts the 4 big weight matrices to bf16 (wconv fold).
// grid: 256 blocks, 256 threads
// ---------------------------------------------------------------------------
__global__ __launch_bounds__(256) void ln_transpose_kernel(
    const float* __restrict__ in0, const float* __restrict__ in1,
    const float* __restrict__ w0, const float* __restrict__ b0,
    const float* __restrict__ w1, const float* __restrict__ b1,
    const float* __restrict__ wxp, const float* __restrict__ wzp,
    const float* __restrict__ wop, const float* __restrict__ wcp,
    short* __restrict__ Wx, short* __restrict__ Wz,
    short* __restrict__ Wo, short* __restrict__ Wc,
    short* __restrict__ xlnz, float* __restrict__ seqT)
{
  __shared__ float tile[32 * 257];
  __shared__ float mu[32], rs[32];
  const int tid = threadIdx.x;
  const int b  = blockIdx.x >> 7;
  const int l0 = (blockIdx.x & 127) << 5;

  // weight conversion: 2048 elements per block (256*2048 = 524288 total)
  {
    int base = (int)blockIdx.x << 11;
    #pragma unroll
    for (int i = 0; i < 8; ++i) {
      int idx = base + (i << 8) + tid;
      if (idx < 65536)       Wx[idx] = f2bf(wxp[idx]);
      else if (idx < 131072) Wz[idx - 65536] = f2bf(wzp[idx - 65536]);
      else if (idx < 196608) Wo[idx - 131072] = f2bf(wop[idx - 131072]);
      else {
        int k = idx - 196608;            // 1280x256 padded
        Wc[k] = ((k >> 8) < 1200) ? f2bf(wcp[k]) : (short)0;
      }
    }
  }

  for (int pass = 0; pass < 2; ++pass) {
    const float* in = pass ? in1 : in0;
    #pragma unroll 8
    for (int i = 0; i < 32; ++i) {
      int e = (i << 8) + tid;
      int c = e >> 5, lo = e & 31;
      tile[lo * 257 + c] = in[((size_t)(b * 256 + c) << 12) + l0 + lo];
    }
    __syncthreads();
    if (tid < 64) {               // one wave: 32 rows x 2 halves
      int r = tid & 31, h = tid >> 5;
      float s = 0.f, ss = 0.f;
      #pragma unroll 16
      for (int c = h * 128; c < h * 128 + 128; ++c) {
        float v = tile[r * 257 + c];
        s += v; ss += v * v;
      }
      s  += __shfl_xor(s, 32, 64);
      ss += __shfl_xor(ss, 32, 64);
      if (h == 0) {
        float m = s * (1.f / 256.f);
        mu[r] = m;
        rs[r] = rsqrtf(ss * (1.f / 256.f) - m * m + 1e-5f);
      }
    }
    __syncthreads();
    const float* w  = pass ? w1 : w0;
    const float* bb = pass ? b1 : b0;
    float wv = w[tid], bv = bb[tid];
    #pragma unroll 8
    for (int i = 0; i < 32; ++i) {
      float v = tile[i * 257 + tid];
      int row = (pass ? 8192 : 0) + (b << 12) + l0 + i;
      xlnz[(size_t)row * 256 + tid] = f2bf((v - mu[i]) * rs[i] * wv + bv);
      if (pass == 0) seqT[(((size_t)b << 12) + l0 + i) * 256 + tid] = v;
    }
    __syncthreads();
  }
}

// ---------------------------------------------------------------------------
// K2: fast 128x128 bf16 MFMA GEMM, C[M,N] = A[M,256] * W[N,256]^T
// EPI 0: f32 store N=256; W switches W0->W1 at m>=Msplit (in_proj x|z)
// EPI 1: bf16 store + f32 ADD[(m&8191)*256+n]  (out_proj + skip, 3 heads)
// EPI 2: conv3d: transposed nontemporal f32x4 store + bias[n]
// ---------------------------------------------------------------------------
template <int EPI>
__global__ __launch_bounds__(256) void gemm_fast(
    const short* __restrict__ A, const short* __restrict__ W0,
    const short* __restrict__ W1, float* __restrict__ Cf,
    short* __restrict__ Cb, const float* __restrict__ ADD,
    const float* __restrict__ bias, int Msplit)
{
  __shared__ short As[4096];   // [128][32] bf16 (global_load_lds layout)
  __shared__ short Bs[4096];
  const int tid  = threadIdx.x;
  const int lane = tid & 63, wave = tid >> 6;
  const int m0 = blockIdx.y << 7;
  const int n0 = blockIdx.x << 7;
  const short* W = (EPI == 0 && m0 >= Msplit) ? W1 : W0;

  const int sr = tid >> 2;
  const int sc = (tid & 3) << 3;
  const int mf = lane & 15, kq = lane >> 4;
  const int wm = (wave & 1) << 6, wn = (wave >> 1) << 6;

  const short* Ar0 = A + (size_t)(m0 + sr) * 256 + sc;
  const short* Ar1 = A + (size_t)(m0 + 64 + sr) * 256 + sc;
  const short* Br0 = W + (size_t)(n0 + sr) * 256 + sc;
  const short* Br1 = W + (size_t)(n0 + 64 + sr) * 256 + sc;
  short* AsW = &As[wave << 9];
  short* BsW = &Bs[wave << 9];

  f32x4 acc[4][4] = {};

  for (int kt = 0; kt < 256; kt += 32) {
    gl_lds16(Ar0 + kt, AsW);
    gl_lds16(Ar1 + kt, AsW + 2048);
    gl_lds16(Br0 + kt, BsW);
    gl_lds16(Br1 + kt, BsW + 2048);
    __syncthreads();
    s16x8 af[4], bfr[4];
    #pragma unroll
    for (int i = 0; i < 4; ++i)
      af[i] = *(const s16x8*)&As[((wm + (i << 4) + mf) << 5) + (kq << 3)];
    #pragma unroll
    for (int j = 0; j < 4; ++j)
      bfr[j] = *(const s16x8*)&Bs[((wn + (j << 4) + mf) << 5) + (kq << 3)];
    #pragma unroll
    for (int i = 0; i < 4; ++i)
      #pragma unroll
      for (int j = 0; j < 4; ++j)
        acc[i][j] = __builtin_amdgcn_mfma_f32_16x16x32_bf16(af[i], bfr[j], acc[i][j], 0, 0, 0);
    __syncthreads();
  }

  if (EPI == 0) {
    #pragma unroll
    for (int i = 0; i < 4; ++i) {
      int gm = m0 + wm + (i << 4) + (kq << 2);
      #pragma unroll
      for (int j = 0; j < 4; ++j) {
        int gn = n0 + wn + (j << 4) + mf;
        #pragma unroll
        for (int r = 0; r < 4; ++r)
          Cf[(size_t)(gm + r) * 256 + gn] = acc[i][j][r];
      }
    }
  } else if (EPI == 1) {
    #pragma unroll
    for (int i = 0; i < 4; ++i) {
      int gm = m0 + wm + (i << 4) + (kq << 2);
      #pragma unroll
      for (int j = 0; j < 4; ++j) {
        int gn = n0 + wn + (j << 4) + mf;
        #pragma unroll
        for (int r = 0; r < 4; ++r) {
          int tok = (gm + r) & 8191;
          float v = acc[i][j][r] + ADD[(size_t)tok * 256 + gn];
          Cb[(size_t)(gm + r) * 256 + gn] = f2bf(v);
        }
      }
    }
  } else {
    const int head = m0 >> 13, bb = (m0 >> 12) & 1, lb = m0 & 4095;
    float* obase = Cf + (size_t)head * (2u * 1200u * 4096u) + (size_t)bb * (1200u * 4096u);
    #pragma unroll
    for (int i = 0; i < 4; ++i) {
      int l = lb + wm + (i << 4) + (kq << 2);
      #pragma unroll
      for (int j = 0; j < 4; ++j) {
        int gn = n0 + wn + (j << 4) + mf;
        if (gn < 1200) {
          float bv = bias[gn];
          f32x4 v = acc[i][j];
          v[0] += bv; v[1] += bv; v[2] += bv; v[3] += bv;
          __builtin_nontemporal_store(v, (f32x4*)&obase[(size_t)gn * 4096 + l]);
        }
      }
    }
  }
}

// ---------------------------------------------------------------------------
// K3: fused front per direction: conv1d+SiLU -> xproj -> dtproj -> scan p1.
// grid: 1024 = dir(2) x b(2) x ch(256); 256 threads (d / (s,j))
// ---------------------------------------------------------------------------
__global__ __launch_bounds__(256) void fused_front(
    const float* __restrict__ x,
    const float* __restrict__ cw0, const float* __restrict__ cb0,
    const float* __restrict__ cw1, const float* __restrict__ cb1,
    const float* __restrict__ xw0, const float* __restrict__ xw1,
    const float* __restrict__ dtw0, const float* __restrict__ dtb0,
    const float* __restrict__ dtw1, const float* __restrict__ dtb1,
    const float* __restrict__ Alog0, const float* __restrict__ Alog1,
    float* __restrict__ xcg, float* __restrict__ dblg,
    float* __restrict__ P, float* __restrict__ Q)
{
  __shared__ float xcs[16 * 256];     // 16 KB
  __shared__ short wxs[256 * 33];     // 16.9 KB, transposed [r][33]
  __shared__ float dls[512];          // 2 KB
  const int tid = threadIdx.x;
  const int dir = blockIdx.x >> 9;
  const int b   = (blockIdx.x >> 8) & 1;
  const int ch  = blockIdx.x & 255;
  const int t0  = ch << 4;
  const float* cw   = dir ? cw1 : cw0;
  const float* cb   = dir ? cb1 : cb0;
  const float* xw   = dir ? xw1 : xw0;
  const float* dtw  = dir ? dtw1 : dtw0;
  const float* dtb  = dir ? dtb1 : dtb0;
  const float* Alog = dir ? Alog1 : Alog0;
  const size_t dS = (size_t)dir * (NTOK * 256);
  const size_t xb = ((size_t)b) << 12;

  // --- conv1d + SiLU (depthwise; thread = channel d) ---
  {
    const int d = tid;
    const float w0 = cw[(d << 2)], w1 = cw[(d << 2) + 1],
                w2 = cw[(d << 2) + 2], w3 = cw[(d << 2) + 3];
    const float bias = cb[d];
    float h0 = 0.f, h1 = 0.f, h2 = 0.f;
    #pragma unroll
    for (int i = 0; i < 3; ++i) {
      int ts = t0 - 3 + i; float v = 0.f;
      if (ts >= 0) { int tn = dir ? 4095 - ts : ts; v = x[(xb + tn) * 256 + d]; }
      h0 = h1; h1 = h2; h2 = v;
    }
    #pragma unroll
    for (int s = 0; s < 16; ++s) {
      int ts = t0 + s;
      int tn = dir ? 4095 - ts : ts;
      float xv = x[(xb + tn) * 256 + d];
      float a = bias + w0 * h0 + w1 * h1 + w2 * h2 + w3 * xv;
      h0 = h1; h1 = h2; h2 = xv;
      float v = a / (1.f + __expf(-a));
      xcs[s * 256 + d] = v;
      xcg[dS + (xb + ts) * 256 + d] = v;
    }
  }
  // --- stage xproj weights (bf16, transposed, stride 33) ---
  #pragma unroll
  for (int i = 0; i < 32; ++i) {
    int flat = (i << 8) + tid;          // j = i, r = tid
    wxs[(flat & 255) * 33 + (flat >> 8)] = f2bf(xw[flat]);
  }
  __syncthreads();

  // --- xproj: thread -> (j = tid&31, s0 = tid>>5 and s0+8) ---
  {
    const int j = tid & 31, s0 = tid >> 5;
    float a0 = 0.f, a1 = 0.f;
    #pragma unroll 8
    for (int r = 0; r < 256; ++r) {
      float w = bf2f(wxs[r * 33 + j]);
      a0 = fmaf(xcs[s0 * 256 + r], w, a0);
      a1 = fmaf(xcs[(s0 + 8) * 256 + r], w, a1);
    }
    dls[(s0 << 5) + j] = a0;
    dls[((s0 + 8) << 5) + j] = a1;
    size_t db = (size_t)dir * 262144 + ((xb + t0) << 5);
    dblg[db + tid] = a0;
    dblg[db + 256 + tid] = a1;
  }
  __syncthreads();

  // --- dtproj (softplus) + scan phase-1 (thread = channel d) ---
  {
    const int d = tid;
    float wrow[16];
    #pragma unroll
    for (int r = 0; r < 16; ++r) wrow[r] = dtw[(d << 4) + r];
    const float bias = dtb[d];
    float Av[8], p[8], q[8];
    #pragma unroll
    for (int n = 0; n < 8; ++n) {
      Av[n] = -expf(Alog[(d << 3) + n]); p[n] = 1.f; q[n] = 0.f;
    }
    for (int s = 0; s < 16; ++s) {
      float a = bias;
      #pragma unroll
      for (int r = 0; r < 16; ++r) a = fmaf(dls[(s << 5) + r], wrow[r], a);
      float dtv = (a > 20.f) ? a : log1pf(__expf(a));
      float xv = xcs[s * 256 + d];
      float du = dtv * xv;
      #pragma unroll
      for (int n = 0; n < 8; ++n) {
        float dA = __expf(dtv * Av[n]);
        p[n] *= dA;
        q[n] = fmaf(q[n], dA, du * dls[(s << 5) + 16 + n]);
      }
    }
    size_t ob = (size_t)dir * 1048576 + ((size_t)((b << 8) + ch) * 8) * 256 + d;
    #pragma unroll
    for (int n = 0; n < 8; ++n) { P[ob + (n << 8)] = p[n]; Q[ob + (n << 8)] = q[n]; }
  }
}

// ---------------------------------------------------------------------------
// K4: inter-chunk scan, both dirs. grid 32 = dir(2) x b(2) x n(8), 256 thr
// ---------------------------------------------------------------------------
__global__ __launch_bounds__(256) void scan_p2(
    const float* __restrict__ P, const float* __restrict__ Q, float* __restrict__ Hs)
{
  const int d = threadIdx.x;
  const int bid = blockIdx.x;
  const int dir = bid >> 4, b = (bid >> 3) & 1, n = bid & 7;
  const size_t dOff = (size_t)dir * 1048576;
  float h = 0.f;
  #pragma unroll 8
  for (int ch = 0; ch < 256; ++ch) {
    size_t i = dOff + ((size_t)((b << 8) + ch) * 8 + n) * 256 + d;
    Hs[i] = h;
    h = fmaf(P[i], h, Q[i]);
  }
}

// ---------------------------------------------------------------------------
// K5: scan phase-3 (replay + dtproj + D + silu(z) gate), both dirs, bf16 out.
// grid: 1024 = dir(2) x b(2) x ch(256), 256 threads (d)
// ---------------------------------------------------------------------------
__global__ __launch_bounds__(256) void scan_p3(
    const float* __restrict__ xcg, const float* __restrict__ dblg,
    const float* __restrict__ dtw0, const float* __restrict__ dtb0,
    const float* __restrict__ dtw1, const float* __restrict__ dtb1,
    const float* __restrict__ Hs, const float* __restrict__ z,
    const float* __restrict__ Alog0, const float* __restrict__ Alog1,
    const float* __restrict__ Dp0, const float* __restrict__ Dp1,
    short* __restrict__ yall)
{
  __shared__ float dl[512];
  const int d = threadIdx.x;
  const int dir = blockIdx.x >> 9;
  const int b   = (blockIdx.x >> 8) & 1;
  const int ch  = blockIdx.x & 255;
  const int t0  = ch << 4;
  const float* dtw  = dir ? dtw1 : dtw0;
  const float* dtb  = dir ? dtb1 : dtb0;
  const float* Alog = dir ? Alog1 : Alog0;
  const float* Dp   = dir ? Dp1 : Dp0;
  const size_t dS = (size_t)dir * (NTOK * 256);
  const size_t xb = ((size_t)b) << 12;
  short* y = yall + (size_t)dir * (NTOK * 256);

  size_t db = (size_t)dir * 262144 + ((xb + t0) << 5);
  dl[d]       = dblg[db + d];
  dl[256 + d] = dblg[db + 256 + d];
  float wrow[16];
  #pragma unroll
  for (int r = 0; r < 16; ++r) wrow[r] = dtw[(d << 4) + r];
  const float bias = dtb[d];
  float Av[8], h[8];
  #pragma unroll
  for (int n = 0; n < 8; ++n) Av[n] = -expf(Alog[(d << 3) + n]);
  size_t hb = (size_t)dir * 1048576 + ((size_t)((b << 8) + ch) * 8) * 256 + d;
  #pragma unroll
  for (int n = 0; n < 8; ++n) h[n] = Hs[hb + (n << 8)];
  const float Dv = Dp[d];
  __syncthreads();
  for (int s = 0; s < 16; ++s) {
    float a = bias;
    #pragma unroll
    for (int r = 0; r < 16; ++r) a = fmaf(dl[(s << 5) + r], wrow[r], a);
    float dtv = (a > 20.f) ? a : log1pf(__expf(a));
    int ts = t0 + s;
    float xv = xcg[dS + (xb + ts) * 256 + d];
    float du = dtv * xv;
    float yv = 0.f;
    #pragma unroll
    for (int n = 0; n < 8; ++n) {
      float dA = __expf(dtv * Av[n]);
      h[n] = fmaf(h[n], dA, du * dl[(s << 5) + 16 + n]);
      yv = fmaf(h[n], dl[(s << 5) + 24 + n], yv);
    }
    yv = fmaf(xv, Dv, yv);
    int tn = dir ? (4095 - ts) : ts;
    size_t zi = (xb + tn) * 256 + d;
    float zv = z[zi];
    y[zi] = f2bf(yv * zv / (1.f + __expf(-zv)));
  }
}

// ---------------------------------------------------------------------------
// K6: RMSNorm all 3 heads (mode=blockIdx.y: 0=avg, 1=yf, 2=yb), bf16 in/out
// ---------------------------------------------------------------------------
__global__ __launch_bounds__(256) void rms_all(
    const short* __restrict__ yf, const short* __restrict__ yb,
    const float* __restrict__ w, short* __restrict__ yn)
{
  const int d = threadIdx.x;
  const int mode = blockIdx.y;
  const size_t tok = blockIdx.x;
  size_t i = tok * 256 + d;
  float v;
  if (mode == 0)      v = 0.5f * (bf2f(yf[i]) + bf2f(yb[i]));
  else if (mode == 1) v = bf2f(yf[i]);
  else                v = bf2f(yb[i]);
  float ss = v * v;
  #pragma unroll
  for (int o = 32; o > 0; o >>= 1) ss += __shfl_xor(ss, o, 64);
  __shared__ float red[4];
  if ((d & 63) == 0) red[d >> 6] = ss;
  __syncthreads();
  float tot = red[0] + red[1] + red[2] + red[3];
  float sc = rsqrtf(tot * (1.f / 256.f) + 1e-5f);
  yn[((size_t)mode * 8192 + tok) * 256 + d] = f2bf(v * sc * w[d]);
}

// ---------------------------------------------------------------------------
extern "C" void kernel_launch(void* const* d_in, const int* in_sizes, int n_in,
                              void* d_out, int out_size, void* d_ws, size_t ws_size,
                              hipStream_t stream) {
  const float* in0        = (const float*)d_in[0];
  const float* in1        = (const float*)d_in[1];
  const float* n0w        = (const float*)d_in[2];
  const float* n0b        = (const float*)d_in[3];
  const float* n1w        = (const float*)d_in[4];
  const float* n1b        = (const float*)d_in[5];
  const float* in_proj_w  = (const float*)d_in[6];
  const float* in_projz_w = (const float*)d_in[7];
  const float* conv1d_w   = (const float*)d_in[8];
  const float* conv1d_b   = (const float*)d_in[9];
  const float* conv1db_w  = (const float*)d_in[10];
  const float* conv1db_b  = (const float*)d_in[11];
  const float* xproj_w    = (const float*)d_in[12];
  const float* xprojb_w   = (const float*)d_in[13];
  const float* dtproj_w   = (const float*)d_in[14];
  const float* dtproj_b   = (const float*)d_in[15];
  const float* dtprojb_w  = (const float*)d_in[16];
  const float* dtprojb_b  = (const float*)d_in[17];
  const float* A_log      = (const float*)d_in[18];
  const float* Ab_log     = (const float*)d_in[19];
  const float* D_p        = (const float*)d_in[20];
  const float* D_b        = (const float*)d_in[21];
  const float* rms_w      = (const float*)d_in[22];
  const float* out_proj_w = (const float*)d_in[23];
  const float* conv3d_w   = (const float*)d_in[24];
  const float* conv3d_b   = (const float*)d_in[25];
  (void)in_sizes; (void)n_in; (void)out_size; (void)ws_size;

  float* ws = (float*)d_ws;
  size_t o = 0;
  short* xlnz = (short*)(ws + o); o += 2097152;   // 16384x256 bf16
  float* seqT = ws + o;           o += 2097152;
  float* x    = ws + o;           o += 2097152;   // x then z contiguous
  float* z    = ws + o;           o += 2097152;
  float* xc2  = ws + o;           o += 4194304;   // 2 dirs x 8192x256 f32
  float* dbl2 = ws + o;           o += 524288;    // 2 dirs x 8192x32
  float* P    = ws + o;           o += 2097152;   // 2 dirs x 1M
  float* Q    = ws + o;           o += 2097152;
  float* Hs   = ws + o;           o += 2097152;
  short* yall = (short*)(ws + o); o += 2097152;   // 2 dirs x 8192x256 bf16
  short* yn   = (short*)(ws + o); o += 3145728;   // 24576x256 bf16
  short* obuf = (short*)(ws + o); o += 3145728;
  short* Wx   = (short*)(ws + o); o += 32768;
  short* Wz   = (short*)(ws + o); o += 32768;
  short* Wo   = (short*)(ws + o); o += 32768;
  short* Wc   = (short*)(ws + o); o += 163840;    // 1280x256 bf16 padded
  float* out  = (float*)d_out;

  dim3 blk(256);

  ln_transpose_kernel<<<dim3(256), blk, 0, stream>>>(
      in0, in1, n0w, n0b, n1w, n1b,
      in_proj_w, in_projz_w, out_proj_w, conv3d_w, Wx, Wz, Wo, Wc,
      xlnz, seqT);

  // in_proj: x|z batched (M=16384, weight switch at 8192)
  gemm_fast<0><<<dim3(2, 128), blk, 0, stream>>>(xlnz, Wx, Wz, x, nullptr, nullptr, nullptr, 8192);

  // both directions: conv+silu -> xproj -> dtproj -> scan p1
  fused_front<<<dim3(1024), blk, 0, stream>>>(
      x, conv1d_w, conv1d_b, conv1db_w, conv1db_b,
      xproj_w, xprojb_w, dtproj_w, dtproj_b, dtprojb_w, dtprojb_b,
      A_log, Ab_log, xc2, dbl2, P, Q);

  scan_p2<<<dim3(32), blk, 0, stream>>>(P, Q, Hs);

  scan_p3<<<dim3(1024), blk, 0, stream>>>(
      xc2, dbl2, dtproj_w, dtproj_b, dtprojb_w, dtprojb_b,
      Hs, z, A_log, Ab_log, D_p, D_b, yall);

  // heads: rms (3 modes) -> out_proj+skip (batched) -> conv3d (batched)
  rms_all<<<dim3(8192, 3), blk, 0, stream>>>(yall, yall + 2097152, rms_w, yn);
  gemm_fast<1><<<dim3(2, 192), blk, 0, stream>>>(yn, Wo, nullptr, nullptr, obuf, seqT, nullptr, 0);
  gemm_fast<2><<<dim3(10, 192), blk, 0, stream>>>(obuf, Wc, nullptr, out, nullptr, nullptr, conv3d_b, 0);
}